// Round 3
// baseline (213.304 us; speedup 1.0000x reference)
//
#include <hip/hip_runtime.h>

typedef __bf16 bf16;
typedef __bf16 bf16x8 __attribute__((ext_vector_type(8)));
typedef float  f32x16 __attribute__((ext_vector_type(16)));
typedef unsigned int u32x4 __attribute__((ext_vector_type(4)));

#define KK     9
#define KDIM   2304
#define KSTEPS 144           // KDIM / 16  (K-steps of the 32x32x16 MFMA)
#define PXW    32            // pixels per WG

__device__ __forceinline__ int sreadi(int v) {
    return __builtin_amdgcn_readfirstlane(v);
}

// bf16 pair unpack (uint = 2 packed bf16)
__device__ __forceinline__ float BL(unsigned v) {
    return __builtin_bit_cast(float, v << 16);
}
__device__ __forceinline__ float BH(unsigned v) {
    return __builtin_bit_cast(float, v & 0xffff0000u);
}

// ---------------------------------------------------------------------------
// Fused prep (unchanged): blocks [0,1024) transpose x -> channels-last bf16;
//             blocks [1024,3328) pack weight -> 32x32x16 A-fragment order:
//   wq[ ((m*144 + ks)*64 + lane)*8 + j ] = W[o = m*32 + (lane&31)]
//                                           [k = ks*16 + (lane>>5)*8 + j]
// ---------------------------------------------------------------------------
__global__ __launch_bounds__(256) void prep_k(const float* __restrict__ x,
                                              const float* __restrict__ w,
                                              bf16* __restrict__ xt,
                                              bf16* __restrict__ wq) {
    int bid = blockIdx.x;
    int tid = threadIdx.x;
    if (bid < 1024) {
        __shared__ bf16 tile[64][72];        // px-major; rows 144 B
        int pt = bid & 63, ct = (bid >> 6) & 3, b = bid >> 8;
        int lane = tid & 63, row = tid >> 6;
        const float* src = x + ((size_t)(b * 256 + ct * 64)) * 4096 + pt * 64;
        #pragma unroll
        for (int cc = row; cc < 64; cc += 4)
            tile[lane][cc] = (bf16)src[(size_t)cc * 4096 + lane];
        __syncthreads();
        bf16* dst = xt + ((size_t)(b * 4096 + pt * 64)) * 256 + ct * 64;
        int p = tid >> 3, j = tid & 7;
        #pragma unroll
        for (int pp = p; pp < 64; pp += 32)
            *reinterpret_cast<bf16x8*>(dst + (size_t)pp * 256 + j * 8) =
                *reinterpret_cast<const bf16x8*>(&tile[pp][j * 8]);
    } else {
        int idx  = (bid - 1024) * 256 + tid;   // < 589824
        int j    = idx & 7;
        int lane = (idx >> 3) & 63;
        int rest = idx >> 9;                   // m*144 + ks, < 1152
        int ks   = rest % KSTEPS;
        int m    = rest / KSTEPS;
        int o    = m * 32 + (lane & 31);
        int k    = ks * 16 + (lane >> 5) * 8 + j;
        int tap  = k >> 8;
        int cc   = k & 255;
        wq[idx] = (bf16)w[(size_t)o * KDIM + cc * KK + tap];
    }
}

// ---------------------------------------------------------------------------
// Producer/consumer wave-specialized sampling + 32x32x16 MFMA GEMM.
// WG = 1024 thr (16 waves), PXW=32, grid 512 -> 2 WG/CU = 32 waves/CU.
//   waves 8..15 = PRODUCERS: per tap, sample 4 pixels/wave (lane>>4 = px,
//     lane&15 = 128-B channel block) -> bilinear blend -> ds_write S[t&1].
//     State: 8 in-flight u32x4 gathers (32 VGPR) + 4 weights; NO accumulator.
//   waves 0..7 = CONSUMERS: wave mt owns out-chans [mt*32,mt*32+32) x 32 px,
//     FULL K=256 per tap (16 MFMAs, one global A b128 + one LDS B b128 each).
//     State: acc f32x16 + streamed A-frags; NO gather state.
// Register pressure split across roles (disjoint branches share the
// allocation) -> both paths fit the 64-VGPR budget of 2 WG/CU; round-2's
// scratch spill (FETCH 83 MB / WRITE 100 MB) is structurally eliminated.
// Pipeline: iter t: producers fill(t)->S[t&1] WHILE consumers gemm(t-1) on
// S[(t-1)&1]; ONE barrier per tap. fill(t) rewrites the buffer gemm(t-2)
// read, which completed before barrier(t-1). Gather latency overlaps MFMA
// on other waves -- no cross-phase register state needed.
// K-halves gone -> no epilogue LDS reduction, consumers store directly.
// LDS swizzle: granule g (16B, ch [g*8,g*8+8)) of row n stored at slot
// g ^ n -> write = uniform bank spread, read (g = s*2+half ^ l32) = 32
// distinct granules (0 conflicts measured in r1/r2 with this pattern).
// XCD band swizzle + per-WG tap rotation kept.
// ---------------------------------------------------------------------------
__global__ __launch_bounds__(1024, 8) void deform_gemm_k(
    const bf16*  __restrict__ xt,
    const float* __restrict__ off,
    const bf16*  __restrict__ wq,
    const float* __restrict__ bias,
    float*       __restrict__ out) {

    __shared__ bf16 S[2][PXW * 256];   // 2 x 16 KB, swizzled 16B granules

    int tid   = threadIdx.x;
    int wavei = sreadi(tid >> 6);   // 0..15
    int lane  = tid & 63;
    int l32   = lane & 31;
    int half  = lane >> 5;

    int bid   = blockIdx.x;                      // 0..511
    int pb    = ((bid & 7) << 6) | (bid >> 3);   // XCD-band pixel-block
    int pix0  = pb * PXW;
    int b     = pix0 >> 12;                      // WG-uniform batch
    int pimgb = pix0 & 4095;
    int obase = b * 73728;                       // base into off[]
    int rot   = ((bid >> 3) & 1) * 4;            // co-resident WG desync

    f32x16 acc;
    #pragma unroll
    for (int r = 0; r < 16; ++r) acc[r] = 0.f;

    // producer-only geometry (harmless for consumers)
    int wp   = wavei - 8;
    int n    = wp * 4 + (lane >> 4);             // S row 0..31
    int pimg = pimgb + n;                        // this lane's pixel
    int cb   = lane & 15;                        // 16B channel block
    const char* xb = (const char*)xt + ((size_t)b << 21) + cb * 16;
    int so0 = ((cb     ) ^ (n & 31)) * 8 + n * 256;   // elem offset, half 0
    int so1 = ((cb + 16) ^ (n & 31)) * 8 + n * 256;   // elem offset, half 1

    for (int t = 0; t < KK; ++t) {
        if (wavei >= 8) {
            // ---------------- PRODUCER: fill(t) -> S[t&1] ----------------
            int tp = t + rot; if (tp >= KK) tp -= KK;
            int ty = tp / 3 - 1;
            int tx = tp % 3 - 1;
            float oy = off[obase + (2 * tp) * 4096 + pimg];
            float ox = off[obase + (2 * tp + 1) * 4096 + pimg];
            float py = (float)((pimg >> 6) + ty) + oy;
            float px = (float)((pimg & 63) + tx) + ox;
            float fy = floorf(py), fx = floorf(px);
            int   y0 = (int)fy,    x0 = (int)fx;
            float wy1 = py - fy, wx1 = px - fx;
            float wy0 = 1.f - wy1, wx0 = 1.f - wx1;
            wy0 = ((unsigned)y0       < 64u) ? wy0 : 0.f;
            wy1 = ((unsigned)(y0 + 1) < 64u) ? wy1 : 0.f;
            wx0 = ((unsigned)x0       < 64u) ? wx0 : 0.f;
            wx1 = ((unsigned)(x0 + 1) < 64u) ? wx1 : 0.f;
            int yc0 = min(max(y0, 0), 63), yc1 = min(max(y0 + 1, 0), 63);
            int xc0 = min(max(x0, 0), 63), xc1 = min(max(x0 + 1, 0), 63);
            unsigned u0 = (unsigned)(yc0 * 64 + xc0) * 512u;
            unsigned u1 = (unsigned)(yc0 * 64 + xc1) * 512u;
            unsigned u2 = (unsigned)(yc1 * 64 + xc0) * 512u;
            unsigned u3 = (unsigned)(yc1 * 64 + xc1) * 512u;
            float w0 = wy0 * wx0, w1 = wy0 * wx1;
            float w2 = wy1 * wx0, w3 = wy1 * wx1;
            // 8 gathers in flight (each: 16 lanes x 16 B = 256 B segment)
            u32x4 g0a = *(const u32x4*)(xb + u0);
            u32x4 g1a = *(const u32x4*)(xb + u1);
            u32x4 g2a = *(const u32x4*)(xb + u2);
            u32x4 g3a = *(const u32x4*)(xb + u3);
            u32x4 g0b = *(const u32x4*)(xb + u0 + 256);
            u32x4 g1b = *(const u32x4*)(xb + u1 + 256);
            u32x4 g2b = *(const u32x4*)(xb + u2 + 256);
            u32x4 g3b = *(const u32x4*)(xb + u3 + 256);
            bf16* Sw = &S[t & 1][0];
            bf16x8 r0, r1;
            #pragma unroll
            for (int q = 0; q < 4; ++q) {
                float lo = fmaf(w0, BL(g0a[q]), fmaf(w1, BL(g1a[q]),
                           fmaf(w2, BL(g2a[q]),      w3 * BL(g3a[q]))));
                float hi = fmaf(w0, BH(g0a[q]), fmaf(w1, BH(g1a[q]),
                           fmaf(w2, BH(g2a[q]),      w3 * BH(g3a[q]))));
                r0[q * 2]     = (bf16)lo;
                r0[q * 2 + 1] = (bf16)hi;
            }
            #pragma unroll
            for (int q = 0; q < 4; ++q) {
                float lo = fmaf(w0, BL(g0b[q]), fmaf(w1, BL(g1b[q]),
                           fmaf(w2, BL(g2b[q]),      w3 * BL(g3b[q]))));
                float hi = fmaf(w0, BH(g0b[q]), fmaf(w1, BH(g1b[q]),
                           fmaf(w2, BH(g2b[q]),      w3 * BH(g3b[q]))));
                r1[q * 2]     = (bf16)lo;
                r1[q * 2 + 1] = (bf16)hi;
            }
            *reinterpret_cast<bf16x8*>(Sw + so0) = r0;
            *reinterpret_cast<bf16x8*>(Sw + so1) = r1;
        } else if (t > 0) {
            // ---------------- CONSUMER: gemm(t-1) on S[(t-1)&1] ----------
            int tg  = t - 1;
            int tap = tg + rot; if (tap >= KK) tap -= KK;
            const bf16* Sr  = &S[tg & 1][0];
            const bf16* ap0 = wq +
                ((size_t)((wavei * KSTEPS + tap * 16) * 64 + lane)) * 8;
            #pragma unroll
            for (int s = 0; s < 16; ++s) {
                bf16x8 a = *reinterpret_cast<const bf16x8*>(ap0 + (size_t)s * 512);
                int gsr = (s * 2 + half) ^ l32;
                bf16x8 bv = *reinterpret_cast<const bf16x8*>(Sr + l32 * 256 + gsr * 8);
                acc = __builtin_amdgcn_mfma_f32_32x32x16_bf16(a, bv, acc, 0, 0, 0);
            }
        }
        __syncthreads();
    }

    // ---- final tap's GEMM + direct store (consumers only) ----
    if (wavei < 8) {
        int tap = (KK - 1) + rot; if (tap >= KK) tap -= KK;
        const bf16* Sr  = &S[(KK - 1) & 1][0];
        const bf16* ap0 = wq +
            ((size_t)((wavei * KSTEPS + tap * 16) * 64 + lane)) * 8;
        #pragma unroll
        for (int s = 0; s < 16; ++s) {
            bf16x8 a = *reinterpret_cast<const bf16x8*>(ap0 + (size_t)s * 512);
            int gsr = (s * 2 + half) ^ l32;
            bf16x8 bv = *reinterpret_cast<const bf16x8*>(Sr + l32 * 256 + gsr * 8);
            acc = __builtin_amdgcn_mfma_f32_32x32x16_bf16(a, bv, acc, 0, 0, 0);
        }
        // C/D layout (32x32x16): col = lane&31, row = (r&3)+8*(r>>2)+4*half
        int m = wavei * 32;
        float* op = out + ((size_t)(b * 256 + m)) * 4096 + pimgb + l32;
        #pragma unroll
        for (int r = 0; r < 16; ++r) {
            int row = (r & 3) + 8 * (r >> 2) + half * 4;
            op[(size_t)row * 4096] = acc[r] + bias[m + row];
        }
    }
}

// ---------------------------------------------------------------------------
extern "C" void kernel_launch(void* const* d_in, const int* in_sizes, int n_in,
                              void* d_out, int out_size, void* d_ws, size_t ws_size,
                              hipStream_t stream) {
    const float* x    = (const float*)d_in[0];   // [4,256,64,64]
    const float* off  = (const float*)d_in[1];   // [4,18,64,64]
    const float* w    = (const float*)d_in[2];   // [256,256,3,3]
    const float* bias = (const float*)d_in[3];   // [256]
    float* out = (float*)d_out;                  // [4,256,64,64]

    bf16* wq = (bf16*)d_ws;                               // 1,179,648 B
    bf16* xt = (bf16*)((char*)d_ws + (size_t)589824 * 2); // 8,388,608 B

    prep_k<<<3328, 256, 0, stream>>>(x, w, xt, wq);
    deform_gemm_k<<<512, 1024, 0, stream>>>(xt, off, wq, bias, out);
}

// Round 4
// 121.433 us; speedup vs baseline: 1.7566x; 1.7566x over previous
//
#include <hip/hip_runtime.h>

typedef __bf16 bf16;
typedef __bf16 bf16x4 __attribute__((ext_vector_type(4)));
typedef __bf16 bf16x8 __attribute__((ext_vector_type(8)));
typedef float  f32x4  __attribute__((ext_vector_type(4)));
typedef float  f32x16 __attribute__((ext_vector_type(16)));

#define KK     9
#define KDIM   2304
#define KSTEPS 144           // KDIM / 16  (K-steps of the 32x32x16 MFMA)
#define PXW    32            // pixels per WG

__device__ __forceinline__ int sreadi(int v) {
    return __builtin_amdgcn_readfirstlane(v);
}

// ---------------------------------------------------------------------------
// prep2_k: fast prep, 1056 blocks x 256 thr.
//  blocks [0,1024): transpose x -> channels-last bf16 xt via LDS f32 tile.
//    Loads are float4 (4/thread vs 16 scalar before); stores bf16x8.
//  blocks [1024,1056): weight pack via LDS staging. Each block owns 8
//    consecutive o-rows: coalesced float4 reads of w (9.4 MB read exactly
//    once, full cacheline use vs ~10% before), bf16 rows staged in LDS,
//    then 9 bf16x8 granules/thread composed and stored coalesced:
//    wq[((m*144+ks)*64 + half*32 + (o&31))*8 + j] = W[o][k=ks*16+half*8+j]
//    (tap = k>>8, cin = k&255; an 8-elem granule never crosses a tap).
// ---------------------------------------------------------------------------
__global__ __launch_bounds__(256) void prep2_k(const float* __restrict__ x,
                                               const float* __restrict__ w,
                                               bf16* __restrict__ xt,
                                               bf16* __restrict__ wq) {
    __shared__ __align__(16) char smem[8 * 2308 * 2];   // 36928 B, aliased
    int bid = blockIdx.x;
    int tid = threadIdx.x;
    if (bid < 1024) {
        float (*tileF)[65] = reinterpret_cast<float(*)[65]>(smem); // 16640 B
        int pt = bid & 63, ct = (bid >> 6) & 3, b = bid >> 8;
        const float* src = x + ((size_t)(b * 256 + ct * 64)) * 4096 + pt * 64;
        int f4 = tid & 15;           // pixel quad
        int cl = tid >> 4;           // channel (base)
        #pragma unroll
        for (int q = 0; q < 4; ++q) {
            int c = q * 16 + cl;
            f32x4 v = *reinterpret_cast<const f32x4*>(src + (size_t)c * 4096 + f4 * 4);
            tileF[f4 * 4 + 0][c] = v[0];
            tileF[f4 * 4 + 1][c] = v[1];
            tileF[f4 * 4 + 2][c] = v[2];
            tileF[f4 * 4 + 3][c] = v[3];
        }
        __syncthreads();
        int j = tid & 7, p0 = tid >> 3;
        bf16* dst = xt + ((size_t)(b * 4096 + pt * 64)) * 256 + ct * 64 + j * 8;
        #pragma unroll
        for (int pp = 0; pp < 2; ++pp) {
            int p = p0 + pp * 32;
            bf16x8 sv;
            #pragma unroll
            for (int k = 0; k < 8; ++k) sv[k] = (bf16)tileF[p][j * 8 + k];
            *reinterpret_cast<bf16x8*>(dst + (size_t)p * 256) = sv;
        }
    } else {
        bf16 (*Wl)[2308] = reinterpret_cast<bf16(*)[2308]>(smem);  // 36928 B
        int wb     = bid - 1024;        // 0..31
        int o_base = wb * 8;
        int m      = o_base >> 5;
        int o31b   = o_base & 31;
        // stage 8 o-rows (coalesced float4) as bf16 in LDS
        #pragma unroll
        for (int pass = 0; pass < 18; ++pass) {
            int i    = pass * 256 + tid;        // < 4608 float4
            int r    = i / 576;
            int col4 = i - r * 576;
            f32x4 v = *reinterpret_cast<const f32x4*>(
                w + (size_t)(o_base + r) * KDIM + col4 * 4);
            Wl[r][col4 * 4 + 0] = (bf16)v[0];
            Wl[r][col4 * 4 + 1] = (bf16)v[1];
            Wl[r][col4 * 4 + 2] = (bf16)v[2];
            Wl[r][col4 * 4 + 3] = (bf16)v[3];
        }
        __syncthreads();
        // compose + store 2304 granules (9 per thread), coalesced in wq
        #pragma unroll
        for (int pass = 0; pass < 9; ++pass) {
            int gid  = pass * 256 + tid;        // < 2304
            int ol   = gid & 7;
            int half = (gid >> 3) & 1;
            int ks   = gid >> 4;                // 0..143
            int kb   = ks * 16 + half * 8;
            int tap  = kb >> 8;
            int cc0  = kb & 255;
            bf16x8 sv;
            #pragma unroll
            for (int j = 0; j < 8; ++j) sv[j] = Wl[ol][(cc0 + j) * 9 + tap];
            size_t g = (size_t)((m * KSTEPS + ks) * 64 + half * 32 + o31b + ol);
            *reinterpret_cast<bf16x8*>(wq + g * 8) = sv;
        }
    }
}

// ---------------------------------------------------------------------------
// deform_gemm_k: EXACT round-1 version (measured 50.8 us, 0 bank conflicts,
// no spill). Fused sampling -> LDS -> 32x32x16 MFMA GEMM with K-split waves.
// WG = 1024 thr (16 waves), PXW=32, grid 512 -> 2 WG/CU = 32 waves/CU.
// Wave (mt = wavei&7, kh = wavei>>3): output chans [mt*32, mt*32+32) x all
// 32 px, K-half kh (within-tap cin 0..127 / 128..255). acc = one f32x16.
// LDS swizzle: full 5-bit XOR (16B slot ^ (row&31)). Double-buffered S, ONE
// barrier per tap; 4 A-frags prefetched before the barrier. XCD band
// swizzle + tap rotation kept.
// ---------------------------------------------------------------------------
__global__ __launch_bounds__(1024, 8) void deform_gemm_k(
    const bf16*  __restrict__ xt,
    const float* __restrict__ off,
    const bf16*  __restrict__ wq,
    const float* __restrict__ bias,
    float*       __restrict__ out) {

    __shared__ bf16 S[2][PXW * 256];   // 2 x 16 KB, swizzled 16B granules

    int tid   = threadIdx.x;
    int wavei = sreadi(tid >> 6);   // 0..15
    int lane  = tid & 63;
    int quad  = lane >> 4;
    int l16   = lane & 15;
    int l32   = lane & 31;
    int half  = lane >> 5;
    int mt    = wavei & 7;          // mtile (32 output channels)
    int kh    = wavei >> 3;         // K-half within each tap
    (void)quad; (void)l16;

    int bid   = blockIdx.x;                      // 0..511
    int pb    = ((bid & 7) << 6) | (bid >> 3);   // XCD-band pixel-block
    int pix0  = pb * PXW;
    int b     = pix0 >> 12;                      // WG-uniform batch
    int pimgb = pix0 & 4095;
    int obase = b * 73728;                       // base into off[]
    unsigned base = (unsigned)b * 1048576u + (unsigned)(lane * 4); // into xt[]
    int rot   = ((bid >> 3) & 1) * 4;            // co-resident WG desync

    f32x16 acc;
    #pragma unroll
    for (int r = 0; r < 16; ++r) acc[r] = 0.f;

    for (int t = 0; t < KK; ++t) {
        int tap = t + rot; if (tap >= KK) tap -= KK;
        int ty = tap / 3 - 1;
        int tx = tap % 3 - 1;
        bf16* Sw = &S[t & 1][0];

        // ---- sampling: wave fills rows n = wavei*2, wavei*2+1 ----
        #pragma unroll
        for (int i = 0; i < 2; ++i) {
            int n    = wavei * 2 + i;
            int pimg = pimgb + n;                          // scalar
            float oy = off[obase + (2 * tap) * 4096 + pimg];      // s_load
            float ox = off[obase + (2 * tap + 1) * 4096 + pimg];  // s_load
            float py = (float)((pimg >> 6) + ty) + oy;
            float px = (float)((pimg & 63) + tx) + ox;
            float fy = floorf(py), fx = floorf(px);
            int   y0 = (int)fy,    x0 = (int)fx;
            float wy1 = py - fy, wx1 = px - fx;
            float wy0 = 1.f - wy1, wx0 = 1.f - wx1;
            wy0 = ((unsigned)y0       < 64u) ? wy0 : 0.f;
            wy1 = ((unsigned)(y0 + 1) < 64u) ? wy1 : 0.f;
            wx0 = ((unsigned)x0       < 64u) ? wx0 : 0.f;
            wx1 = ((unsigned)(x0 + 1) < 64u) ? wx1 : 0.f;
            int yc0 = min(max(y0, 0), 63), yc1 = min(max(y0 + 1, 0), 63);
            int xc0 = min(max(x0, 0), 63), xc1 = min(max(x0 + 1, 0), 63);
            int u0 = sreadi((yc0 * 64 + xc0) * 256);
            int u1 = sreadi((yc0 * 64 + xc1) * 256);
            int u2 = sreadi((yc1 * 64 + xc0) * 256);
            int u3 = sreadi((yc1 * 64 + xc1) * 256);
            float w0 = __builtin_bit_cast(float, sreadi(__builtin_bit_cast(int, wy0 * wx0)));
            float w1 = __builtin_bit_cast(float, sreadi(__builtin_bit_cast(int, wy0 * wx1)));
            float w2 = __builtin_bit_cast(float, sreadi(__builtin_bit_cast(int, wy1 * wx0)));
            float w3 = __builtin_bit_cast(float, sreadi(__builtin_bit_cast(int, wy1 * wx1)));
            bf16x4 v0 = *reinterpret_cast<const bf16x4*>(xt + base + (unsigned)u0);
            bf16x4 v1 = *reinterpret_cast<const bf16x4*>(xt + base + (unsigned)u1);
            bf16x4 v2 = *reinterpret_cast<const bf16x4*>(xt + base + (unsigned)u2);
            bf16x4 v3 = *reinterpret_cast<const bf16x4*>(xt + base + (unsigned)u3);
            float a0 = w0 * (float)v0[0] + w1 * (float)v1[0]
                     + w2 * (float)v2[0] + w3 * (float)v3[0];
            float a1 = w0 * (float)v0[1] + w1 * (float)v1[1]
                     + w2 * (float)v2[1] + w3 * (float)v3[1];
            float a2 = w0 * (float)v0[2] + w1 * (float)v1[2]
                     + w2 * (float)v2[2] + w3 * (float)v3[2];
            float a3 = w0 * (float)v0[3] + w1 * (float)v1[3]
                     + w2 * (float)v2[3] + w3 * (float)v3[3];
            bf16x4 sv;
            sv[0] = (bf16)a0; sv[1] = (bf16)a1;
            sv[2] = (bf16)a2; sv[3] = (bf16)a3;
            // ch = lane*4 -> 16B slot (lane>>1), half (lane&1); 5-bit XOR
            int gs = (lane >> 1) ^ (n & 31);
            *reinterpret_cast<bf16x4*>(Sw + n * 256 + gs * 8 + (lane & 1) * 4) = sv;
        }

        // A pointer for this tap; prefetch 4 frags before the barrier so
        // the barrier's vmcnt(0) drain covers their latency.
        const bf16* ap0 = wq +
            ((size_t)(((mt * KSTEPS) + tap * 16 + kh * 8) * 64 + lane)) * 8;
        bf16x8 a0 = *reinterpret_cast<const bf16x8*>(ap0);
        bf16x8 a1 = *reinterpret_cast<const bf16x8*>(ap0 + 512);
        bf16x8 a2 = *reinterpret_cast<const bf16x8*>(ap0 + 1024);
        bf16x8 a3 = *reinterpret_cast<const bf16x8*>(ap0 + 1536);

        __syncthreads();

        // ---- GEMM over this wave's K-half (128 of the tap's 256) ----
        const bf16* Sr = Sw;
        #pragma unroll
        for (int kk2 = 0; kk2 < 8; ++kk2) {
            bf16x8 a;
            if      (kk2 == 0) a = a0;
            else if (kk2 == 1) a = a1;
            else if (kk2 == 2) a = a2;
            else if (kk2 == 3) a = a3;
            else a = *reinterpret_cast<const bf16x8*>(ap0 + (size_t)kk2 * 512);
            int s  = kh * 8 + kk2;              // K-step within tap, 0..15
            int g  = s * 2 + half;              // 16B slot (cin base >> 3)
            int gs = g ^ l32;                   // row = l32 (pixel/col)
            bf16x8 bf = *reinterpret_cast<const bf16x8*>(Sr + l32 * 256 + gs * 8);
            acc = __builtin_amdgcn_mfma_f32_32x32x16_bf16(a, bf, acc, 0, 0, 0);
        }
        // no second barrier: next tap writes the OTHER buffer; re-write of
        // this buffer (t+2) is ordered behind barrier t+1.
    }

    // ---- epilogue: sum the two K-halves through LDS, then store ----
    __syncthreads();                 // all GEMM reads of S done
    float* Sf = reinterpret_cast<float*>(&S[0][0]);   // 8192 f32 = 32 KB
    if (wavei >= 8) {
        int wb = (wavei - 8) * 64 + lane;
        #pragma unroll
        for (int r = 0; r < 16; ++r)
            Sf[r * 512 + wb] = acc[r];   // lane-major: conflict-free b32
    }
    __syncthreads();
    if (wavei < 8) {
        // C/D layout (32x32x16): col = lane&31, row = (r&3)+8*(r>>2)+4*half
        int wb   = wavei * 64 + lane;
        int m    = mt * 32;              // mt == wavei here (kh == 0)
        int pimg = pimgb + l32;
        float* op = out + ((size_t)(b * 256 + m)) * 4096 + pimg;
        #pragma unroll
        for (int r = 0; r < 16; ++r) {
            int row = (r & 3) + 8 * (r >> 2) + half * 4;
            float v = acc[r] + Sf[r * 512 + wb] + bias[m + row];
            op[(size_t)row * 4096] = v;
        }
    }
}

// ---------------------------------------------------------------------------
extern "C" void kernel_launch(void* const* d_in, const int* in_sizes, int n_in,
                              void* d_out, int out_size, void* d_ws, size_t ws_size,
                              hipStream_t stream) {
    const float* x    = (const float*)d_in[0];   // [4,256,64,64]
    const float* off  = (const float*)d_in[1];   // [4,18,64,64]
    const float* w    = (const float*)d_in[2];   // [256,256,3,3]
    const float* bias = (const float*)d_in[3];   // [256]
    float* out = (float*)d_out;                  // [4,256,64,64]

    bf16* wq = (bf16*)d_ws;                               // 1,179,648 B
    bf16* xt = (bf16*)((char*)d_ws + (size_t)589824 * 2); // 8,388,608 B

    prep2_k<<<1056, 256, 0, stream>>>(x, w, xt, wq);
    deform_gemm_k<<<512, 1024, 0, stream>>>(xt, off, wq, bias, out);
}

// Round 5
// 121.328 us; speedup vs baseline: 1.7581x; 1.0009x over previous
//
#include <hip/hip_runtime.h>

typedef __bf16 bf16;
typedef __bf16 bf16x4 __attribute__((ext_vector_type(4)));
typedef __bf16 bf16x8 __attribute__((ext_vector_type(8)));
typedef float  f32x4  __attribute__((ext_vector_type(4)));
typedef float  f32x16 __attribute__((ext_vector_type(16)));
typedef unsigned int u32x4 __attribute__((ext_vector_type(4)));

#define KK     9
#define KDIM   2304
#define KSTEPS 144           // KDIM / 16  (K-steps of the 32x32x16 MFMA)
#define PXW    32            // pixels per WG

__device__ __forceinline__ int sreadi(int v) {
    return __builtin_amdgcn_readfirstlane(v);
}

// bf16 pair unpack (uint = 2 packed bf16)
__device__ __forceinline__ float BL(unsigned v) {
    return __builtin_bit_cast(float, v << 16);
}
__device__ __forceinline__ float BH(unsigned v) {
    return __builtin_bit_cast(float, v & 0xffff0000u);
}

// ---------------------------------------------------------------------------
// prep2_k: unchanged from round 4 (verified).
// ---------------------------------------------------------------------------
__global__ __launch_bounds__(256) void prep2_k(const float* __restrict__ x,
                                               const float* __restrict__ w,
                                               bf16* __restrict__ xt,
                                               bf16* __restrict__ wq) {
    __shared__ __align__(16) char smem[8 * 2308 * 2];   // 36928 B, aliased
    int bid = blockIdx.x;
    int tid = threadIdx.x;
    if (bid < 1024) {
        float (*tileF)[65] = reinterpret_cast<float(*)[65]>(smem); // 16640 B
        int pt = bid & 63, ct = (bid >> 6) & 3, b = bid >> 8;
        const float* src = x + ((size_t)(b * 256 + ct * 64)) * 4096 + pt * 64;
        int f4 = tid & 15;           // pixel quad
        int cl = tid >> 4;           // channel (base)
        #pragma unroll
        for (int q = 0; q < 4; ++q) {
            int c = q * 16 + cl;
            f32x4 v = *reinterpret_cast<const f32x4*>(src + (size_t)c * 4096 + f4 * 4);
            tileF[f4 * 4 + 0][c] = v[0];
            tileF[f4 * 4 + 1][c] = v[1];
            tileF[f4 * 4 + 2][c] = v[2];
            tileF[f4 * 4 + 3][c] = v[3];
        }
        __syncthreads();
        int j = tid & 7, p0 = tid >> 3;
        bf16* dst = xt + ((size_t)(b * 4096 + pt * 64)) * 256 + ct * 64 + j * 8;
        #pragma unroll
        for (int pp = 0; pp < 2; ++pp) {
            int p = p0 + pp * 32;
            bf16x8 sv;
            #pragma unroll
            for (int k = 0; k < 8; ++k) sv[k] = (bf16)tileF[p][j * 8 + k];
            *reinterpret_cast<bf16x8*>(dst + (size_t)p * 256) = sv;
        }
    } else {
        bf16 (*Wl)[2308] = reinterpret_cast<bf16(*)[2308]>(smem);  // 36928 B
        int wb     = bid - 1024;        // 0..31
        int o_base = wb * 8;
        int m      = o_base >> 5;
        int o31b   = o_base & 31;
        // stage 8 o-rows (coalesced float4) as bf16 in LDS
        #pragma unroll
        for (int pass = 0; pass < 18; ++pass) {
            int i    = pass * 256 + tid;        // < 4608 float4
            int r    = i / 576;
            int col4 = i - r * 576;
            f32x4 v = *reinterpret_cast<const f32x4*>(
                w + (size_t)(o_base + r) * KDIM + col4 * 4);
            Wl[r][col4 * 4 + 0] = (bf16)v[0];
            Wl[r][col4 * 4 + 1] = (bf16)v[1];
            Wl[r][col4 * 4 + 2] = (bf16)v[2];
            Wl[r][col4 * 4 + 3] = (bf16)v[3];
        }
        __syncthreads();
        // compose + store 2304 granules (9 per thread), coalesced in wq
        #pragma unroll
        for (int pass = 0; pass < 9; ++pass) {
            int gid  = pass * 256 + tid;        // < 2304
            int ol   = gid & 7;
            int half = (gid >> 3) & 1;
            int ks   = gid >> 4;                // 0..143
            int kb   = ks * 16 + half * 8;
            int tap  = kb >> 8;
            int cc0  = kb & 255;
            bf16x8 sv;
            #pragma unroll
            for (int j = 0; j < 8; ++j) sv[j] = Wl[ol][(cc0 + j) * 9 + tap];
            size_t g = (size_t)((m * KSTEPS + ks) * 64 + half * 32 + o31b + ol);
            *reinterpret_cast<bf16x8*>(wq + g * 8) = sv;
        }
    }
}

// ---------------------------------------------------------------------------
// deform_gemm_k: round-1 structure (verified: 0 conflicts, no spill) with
// lane-split sampling + detangled/prefetched offset loads.
//   - Sampling: lane-half h owns px n = wavei*2+h. Params computed ONCE per
//     px (in its 32 lanes) instead of 64-lane-redundantly twice; weights and
//     gather addresses are per-lane (no readfirstlane broadcasts). Each lane
//     gathers its own 16-B channel block per corner (4 x dwordx4 per wave,
//     half-wave = 512-B segment), unpacks 8 ch, blends, writes ONE b128 to
//     LDS. Sampling issue ~130 instr/tap/wave vs ~520 before.
//   - Offset loads are per-lane GLOBAL loads (vmcnt domain -- no lgkmcnt
//     entanglement with the GEMM's ds_reads) and are issued one tap AHEAD
//     (after the barrier, before gemm(t)): 2 VGPRs of cross-phase state,
//     latency hidden under the GEMM.
//   - GEMM, swizzle (granule g of row n at slot g^n), double-buffer, one
//     barrier per tap, 4-frag A prefetch, K-half epilogue reduction, XCD
//     band swizzle, tap rotation: all unchanged from round 1.
// ---------------------------------------------------------------------------
__global__ __launch_bounds__(1024, 8) void deform_gemm_k(
    const bf16*  __restrict__ xt,
    const float* __restrict__ off,
    const bf16*  __restrict__ wq,
    const float* __restrict__ bias,
    float*       __restrict__ out) {

    __shared__ bf16 S[2][PXW * 256];   // 2 x 16 KB, swizzled 16B granules

    int tid   = threadIdx.x;
    int wavei = sreadi(tid >> 6);   // 0..15
    int lane  = tid & 63;
    int l32   = lane & 31;
    int half  = lane >> 5;
    int mt    = wavei & 7;          // mtile (32 output channels)
    int kh    = wavei >> 3;         // K-half within each tap

    int bid   = blockIdx.x;                      // 0..511
    int pb    = ((bid & 7) << 6) | (bid >> 3);   // XCD-band pixel-block
    int pix0  = pb * PXW;
    int b     = pix0 >> 12;                      // WG-uniform batch
    int pimgb = pix0 & 4095;
    int obase = b * 73728;                       // base into off[]
    int rot   = ((bid >> 3) & 1) * 4;            // co-resident WG desync

    // this lane's pixel (row n of S) and gather base
    int n     = wavei * 2 + half;                // S row 0..31
    int pimg  = pimgb + n;
    int py_i  = pimg >> 6, px_i = pimg & 63;
    const char* xb = (const char*)xt + ((size_t)b << 21) + l32 * 16;

    f32x16 acc;
    #pragma unroll
    for (int r = 0; r < 16; ++r) acc[r] = 0.f;

    // offset prefetch state (tap for t=0)
    float oyC = off[obase + (2 * rot) * 4096 + pimg];
    float oxC = off[obase + (2 * rot + 1) * 4096 + pimg];

    for (int t = 0; t < KK; ++t) {
        int tap = t + rot; if (tap >= KK) tap -= KK;
        int ty = tap / 3 - 1;
        int tx = tap % 3 - 1;
        bf16* Sw = &S[t & 1][0];

        // ---- sampling (lane-split): px n, channels [l32*8, l32*8+8) ----
        float py = (float)(py_i + ty) + oyC;
        float px = (float)(px_i + tx) + oxC;
        float fy = floorf(py), fx = floorf(px);
        int   y0 = (int)fy,    x0 = (int)fx;
        float wy1 = py - fy, wx1 = px - fx;
        float wy0 = 1.f - wy1, wx0 = 1.f - wx1;
        wy0 = ((unsigned)y0       < 64u) ? wy0 : 0.f;
        wy1 = ((unsigned)(y0 + 1) < 64u) ? wy1 : 0.f;
        wx0 = ((unsigned)x0       < 64u) ? wx0 : 0.f;
        wx1 = ((unsigned)(x0 + 1) < 64u) ? wx1 : 0.f;
        int yc0 = min(max(y0, 0), 63), yc1 = min(max(y0 + 1, 0), 63);
        int xc0 = min(max(x0, 0), 63), xc1 = min(max(x0 + 1, 0), 63);
        unsigned u0 = (unsigned)(yc0 * 64 + xc0) * 512u;
        unsigned u1 = (unsigned)(yc0 * 64 + xc1) * 512u;
        unsigned u2 = (unsigned)(yc1 * 64 + xc0) * 512u;
        unsigned u3 = (unsigned)(yc1 * 64 + xc1) * 512u;
        float w0 = wy0 * wx0, w1 = wy0 * wx1;
        float w2 = wy1 * wx0, w3 = wy1 * wx1;
        u32x4 g0 = *(const u32x4*)(xb + u0);
        u32x4 g1 = *(const u32x4*)(xb + u1);
        u32x4 g2 = *(const u32x4*)(xb + u2);
        u32x4 g3 = *(const u32x4*)(xb + u3);
        bf16x8 sv;
        #pragma unroll
        for (int q = 0; q < 4; ++q) {
            float lo = fmaf(w0, BL(g0[q]), fmaf(w1, BL(g1[q]),
                       fmaf(w2, BL(g2[q]),      w3 * BL(g3[q]))));
            float hi = fmaf(w0, BH(g0[q]), fmaf(w1, BH(g1[q]),
                       fmaf(w2, BH(g2[q]),      w3 * BH(g3[q]))));
            sv[q * 2]     = (bf16)lo;
            sv[q * 2 + 1] = (bf16)hi;
        }
        // granule l32 of row n (ch block l32*8), XOR-swizzled; one b128
        int gsw = l32 ^ (n & 31);
        *reinterpret_cast<bf16x8*>(Sw + n * 256 + gsw * 8) = sv;

        // A pointer for this tap; prefetch 4 frags before the barrier so
        // the barrier's vmcnt(0) drain covers their latency.
        const bf16* ap0 = wq +
            ((size_t)(((mt * KSTEPS) + tap * 16 + kh * 8) * 64 + lane)) * 8;
        bf16x8 a0 = *reinterpret_cast<const bf16x8*>(ap0);
        bf16x8 a1 = *reinterpret_cast<const bf16x8*>(ap0 + 512);
        bf16x8 a2 = *reinterpret_cast<const bf16x8*>(ap0 + 1024);
        bf16x8 a3 = *reinterpret_cast<const bf16x8*>(ap0 + 1536);

        __syncthreads();

        // ---- offset prefetch for tap t+1 (flies across the GEMM) ----
        if (t < KK - 1) {
            int tn = tap + 1; if (tn >= KK) tn = 0;
            oyC = off[obase + (2 * tn) * 4096 + pimg];
            oxC = off[obase + (2 * tn + 1) * 4096 + pimg];
        }

        // ---- GEMM over this wave's K-half (128 of the tap's 256) ----
        const bf16* Sr = Sw;
        #pragma unroll
        for (int kk2 = 0; kk2 < 8; ++kk2) {
            bf16x8 a;
            if      (kk2 == 0) a = a0;
            else if (kk2 == 1) a = a1;
            else if (kk2 == 2) a = a2;
            else if (kk2 == 3) a = a3;
            else a = *reinterpret_cast<const bf16x8*>(ap0 + (size_t)kk2 * 512);
            int s  = kh * 8 + kk2;              // K-step within tap, 0..15
            int g  = s * 2 + half;              // 16B slot (cin base >> 3)
            int gs = g ^ l32;                   // row = l32 (pixel/col)
            bf16x8 bv = *reinterpret_cast<const bf16x8*>(Sr + l32 * 256 + gs * 8);
            acc = __builtin_amdgcn_mfma_f32_32x32x16_bf16(a, bv, acc, 0, 0, 0);
        }
        // no second barrier: next tap writes the OTHER buffer; re-write of
        // this buffer (t+2) is ordered behind barrier t+1.
    }

    // ---- epilogue: sum the two K-halves through LDS, then store ----
    __syncthreads();                 // all GEMM reads of S done
    float* Sf = reinterpret_cast<float*>(&S[0][0]);   // 8192 f32 = 32 KB
    if (wavei >= 8) {
        int wb = (wavei - 8) * 64 + lane;
        #pragma unroll
        for (int r = 0; r < 16; ++r)
            Sf[r * 512 + wb] = acc[r];   // lane-major: conflict-free b32
    }
    __syncthreads();
    if (wavei < 8) {
        // C/D layout (32x32x16): col = lane&31, row = (r&3)+8*(r>>2)+4*half
        int wb   = wavei * 64 + lane;
        int m    = mt * 32;              // mt == wavei here (kh == 0)
        int pimo = pimgb + l32;
        float* op = out + ((size_t)(b * 256 + m)) * 4096 + pimo;
        #pragma unroll
        for (int r = 0; r < 16; ++r) {
            int row = (r & 3) + 8 * (r >> 2) + half * 4;
            float v = acc[r] + Sf[r * 512 + wb] + bias[m + row];
            op[(size_t)row * 4096] = v;
        }
    }
}

// ---------------------------------------------------------------------------
extern "C" void kernel_launch(void* const* d_in, const int* in_sizes, int n_in,
                              void* d_out, int out_size, void* d_ws, size_t ws_size,
                              hipStream_t stream) {
    const float* x    = (const float*)d_in[0];   // [4,256,64,64]
    const float* off  = (const float*)d_in[1];   // [4,18,64,64]
    const float* w    = (const float*)d_in[2];   // [256,256,3,3]
    const float* bias = (const float*)d_in[3];   // [256]
    float* out = (float*)d_out;                  // [4,256,64,64]

    bf16* wq = (bf16*)d_ws;                               // 1,179,648 B
    bf16* xt = (bf16*)((char*)d_ws + (size_t)589824 * 2); // 8,388,608 B

    prep2_k<<<1056, 256, 0, stream>>>(x, w, xt, wq);
    deform_gemm_k<<<512, 1024, 0, stream>>>(xt, off, wq, bias, out);
}

// Round 6
// 112.300 us; speedup vs baseline: 1.8994x; 1.0804x over previous
//
#include <hip/hip_runtime.h>

typedef __bf16 bf16;
typedef __bf16 bf16x4 __attribute__((ext_vector_type(4)));
typedef __bf16 bf16x8 __attribute__((ext_vector_type(8)));
typedef float  f32x4  __attribute__((ext_vector_type(4)));
typedef float  f32x16 __attribute__((ext_vector_type(16)));
typedef unsigned int u32x4 __attribute__((ext_vector_type(4)));

#define KK     9
#define KDIM   2304
#define KSTEPS 144           // KDIM / 16  (K-steps of the 32x32x16 MFMA)
#define PXW    64            // pixels per WG (doubled: halves A-traffic/output)

__device__ __forceinline__ int sreadi(int v) {
    return __builtin_amdgcn_readfirstlane(v);
}

// bf16 pair unpack (uint = 2 packed bf16)
__device__ __forceinline__ float BL(unsigned v) {
    return __builtin_bit_cast(float, v << 16);
}
__device__ __forceinline__ float BH(unsigned v) {
    return __builtin_bit_cast(float, v & 0xffff0000u);
}

// ---------------------------------------------------------------------------
// prep2_k: unchanged (verified rounds 4-5).
// ---------------------------------------------------------------------------
__global__ __launch_bounds__(256) void prep2_k(const float* __restrict__ x,
                                               const float* __restrict__ w,
                                               bf16* __restrict__ xt,
                                               bf16* __restrict__ wq) {
    __shared__ __align__(16) char smem[8 * 2308 * 2];   // 36928 B, aliased
    int bid = blockIdx.x;
    int tid = threadIdx.x;
    if (bid < 1024) {
        float (*tileF)[65] = reinterpret_cast<float(*)[65]>(smem); // 16640 B
        int pt = bid & 63, ct = (bid >> 6) & 3, b = bid >> 8;
        const float* src = x + ((size_t)(b * 256 + ct * 64)) * 4096 + pt * 64;
        int f4 = tid & 15;           // pixel quad
        int cl = tid >> 4;           // channel (base)
        #pragma unroll
        for (int q = 0; q < 4; ++q) {
            int c = q * 16 + cl;
            f32x4 v = *reinterpret_cast<const f32x4*>(src + (size_t)c * 4096 + f4 * 4);
            tileF[f4 * 4 + 0][c] = v[0];
            tileF[f4 * 4 + 1][c] = v[1];
            tileF[f4 * 4 + 2][c] = v[2];
            tileF[f4 * 4 + 3][c] = v[3];
        }
        __syncthreads();
        int j = tid & 7, p0 = tid >> 3;
        bf16* dst = xt + ((size_t)(b * 4096 + pt * 64)) * 256 + ct * 64 + j * 8;
        #pragma unroll
        for (int pp = 0; pp < 2; ++pp) {
            int p = p0 + pp * 32;
            bf16x8 sv;
            #pragma unroll
            for (int k = 0; k < 8; ++k) sv[k] = (bf16)tileF[p][j * 8 + k];
            *reinterpret_cast<bf16x8*>(dst + (size_t)p * 256) = sv;
        }
    } else {
        bf16 (*Wl)[2308] = reinterpret_cast<bf16(*)[2308]>(smem);  // 36928 B
        int wb     = bid - 1024;        // 0..31
        int o_base = wb * 8;
        int m      = o_base >> 5;
        int o31b   = o_base & 31;
        // stage 8 o-rows (coalesced float4) as bf16 in LDS
        #pragma unroll
        for (int pass = 0; pass < 18; ++pass) {
            int i    = pass * 256 + tid;        // < 4608 float4
            int r    = i / 576;
            int col4 = i - r * 576;
            f32x4 v = *reinterpret_cast<const f32x4*>(
                w + (size_t)(o_base + r) * KDIM + col4 * 4);
            Wl[r][col4 * 4 + 0] = (bf16)v[0];
            Wl[r][col4 * 4 + 1] = (bf16)v[1];
            Wl[r][col4 * 4 + 2] = (bf16)v[2];
            Wl[r][col4 * 4 + 3] = (bf16)v[3];
        }
        __syncthreads();
        // compose + store 2304 granules (9 per thread), coalesced in wq
        #pragma unroll
        for (int pass = 0; pass < 9; ++pass) {
            int gid  = pass * 256 + tid;        // < 2304
            int ol   = gid & 7;
            int half = (gid >> 3) & 1;
            int ks   = gid >> 4;                // 0..143
            int kb   = ks * 16 + half * 8;
            int tap  = kb >> 8;
            int cc0  = kb & 255;
            bf16x8 sv;
            #pragma unroll
            for (int j = 0; j < 8; ++j) sv[j] = Wl[ol][(cc0 + j) * 9 + tap];
            size_t g = (size_t)((m * KSTEPS + ks) * 64 + half * 32 + o31b + ol);
            *reinterpret_cast<bf16x8*>(wq + g * 8) = sv;
        }
    }
}

// ---------------------------------------------------------------------------
// deform_gemm_k v6: PXW=64, grid 256 (1 WG/CU forced by grid), 16 waves.
// Wave (mt = wavei&7, kh = wavei>>3): 32 out-chans x 64 px (2 ntiles,
// acc = 2 x f32x16) x K=128 per tap. A-frags per wave-tap unchanged (8) but
// feed 2x output -> total weight L2 traffic 590 -> 295 MB (the r5 counter
// analysis showed per-CU VMEM bandwidth, dominated by A re-reads, is the
// bottleneck: 384 KB/CU/tap -> 257 KB/CU/tap now).
// Grid=256 caps occupancy at 1 WG/CU regardless of VGPRs, so budget is
// raised to 128 (__launch_bounds__(1024,4)): acc 32 + A-prefetch 32 +
// gather 16 + misc fits ~100 VGPR with NO spill (r2/r3 spilled at the
// 64-VGPR budget; the FETCH/WRITE counters verify).
// Sampling: half-wave h of wave w fills rows n = w*4+h*2+{0,1} (two
// sequential r5-style bodies: lane covers ch-block l32, 4 x dwordx4
// corner gathers, blend, one swizzled b128 ds_write).
// All verified r1/r5 structure kept: granule-XOR swizzle (0 conflicts),
// double-buffered S with ONE barrier per tap, A-frag prefetch before the
// barrier, per-tap off prefetch after it, kh-epilogue reduction via LDS,
// XCD band swizzle (8 XCDs x 32 CUs; each XCD touches one batch's 2 MB xt
// slice -> L2-resident), tap rotation across CUs.
// ---------------------------------------------------------------------------
__global__ __launch_bounds__(1024, 4) void deform_gemm_k(
    const bf16*  __restrict__ xt,
    const float* __restrict__ off,
    const bf16*  __restrict__ wq,
    const float* __restrict__ bias,
    float*       __restrict__ out) {

    __shared__ bf16 S[2][PXW * 256];   // 2 x 32 KB, swizzled 16B granules

    int tid   = threadIdx.x;
    int wavei = sreadi(tid >> 6);   // 0..15
    int lane  = tid & 63;
    int l32   = lane & 31;
    int half  = lane >> 5;
    int mt    = wavei & 7;          // mtile (32 output channels)
    int kh    = wavei >> 3;         // K-half within each tap

    int bid   = blockIdx.x;                      // 0..255
    int pb    = ((bid & 7) << 5) | (bid >> 3);   // XCD-band pixel-block
    int pix0  = pb * PXW;
    int b     = pix0 >> 12;                      // WG-uniform batch
    int pimgb = pix0 & 4095;
    int obase = b * 73728;                       // base into off[]
    int rot   = (bid >> 3) & 7;                  // tap-phase desync across CUs

    // sampling geometry: this lane serves rows n0, n1
    int n0    = wavei * 4 + half * 2;
    int n1    = n0 + 1;
    int pimg0 = pimgb + n0;
    int pimg1 = pimgb + n1;
    const char* xb = (const char*)xt + ((size_t)b << 21) + l32 * 16;

    f32x16 acc0, acc1;
    #pragma unroll
    for (int r = 0; r < 16; ++r) { acc0[r] = 0.f; acc1[r] = 0.f; }

    // one sampling body: row n / pixel pimg with offsets (oy, ox)
    auto body = [&](int n, int pimg, float oy, float ox, int ty, int tx,
                    bf16* Sw) {
        float py = (float)((pimg >> 6) + ty) + oy;
        float px = (float)((pimg & 63) + tx) + ox;
        float fy = floorf(py), fx = floorf(px);
        int   y0 = (int)fy,    x0 = (int)fx;
        float wy1 = py - fy, wx1 = px - fx;
        float wy0 = 1.f - wy1, wx0 = 1.f - wx1;
        wy0 = ((unsigned)y0       < 64u) ? wy0 : 0.f;
        wy1 = ((unsigned)(y0 + 1) < 64u) ? wy1 : 0.f;
        wx0 = ((unsigned)x0       < 64u) ? wx0 : 0.f;
        wx1 = ((unsigned)(x0 + 1) < 64u) ? wx1 : 0.f;
        int yc0 = min(max(y0, 0), 63), yc1 = min(max(y0 + 1, 0), 63);
        int xc0 = min(max(x0, 0), 63), xc1 = min(max(x0 + 1, 0), 63);
        unsigned u0 = (unsigned)(yc0 * 64 + xc0) * 512u;
        unsigned u1 = (unsigned)(yc0 * 64 + xc1) * 512u;
        unsigned u2 = (unsigned)(yc1 * 64 + xc0) * 512u;
        unsigned u3 = (unsigned)(yc1 * 64 + xc1) * 512u;
        float w0 = wy0 * wx0, w1 = wy0 * wx1;
        float w2 = wy1 * wx0, w3 = wy1 * wx1;
        u32x4 g0 = *(const u32x4*)(xb + u0);
        u32x4 g1 = *(const u32x4*)(xb + u1);
        u32x4 g2 = *(const u32x4*)(xb + u2);
        u32x4 g3 = *(const u32x4*)(xb + u3);
        bf16x8 sv;
        #pragma unroll
        for (int q = 0; q < 4; ++q) {
            float lo = fmaf(w0, BL(g0[q]), fmaf(w1, BL(g1[q]),
                       fmaf(w2, BL(g2[q]),      w3 * BL(g3[q]))));
            float hi = fmaf(w0, BH(g0[q]), fmaf(w1, BH(g1[q]),
                       fmaf(w2, BH(g2[q]),      w3 * BH(g3[q]))));
            sv[q * 2]     = (bf16)lo;
            sv[q * 2 + 1] = (bf16)hi;
        }
        int gsw = l32 ^ (n & 31);              // granule-XOR swizzle
        *reinterpret_cast<bf16x8*>(Sw + n * 256 + gsw * 8) = sv;
    };

    // off prefetch for t=0
    float oy0 = off[obase + (2 * rot)     * 4096 + pimg0];
    float ox0 = off[obase + (2 * rot + 1) * 4096 + pimg0];
    float oy1 = off[obase + (2 * rot)     * 4096 + pimg1];
    float ox1 = off[obase + (2 * rot + 1) * 4096 + pimg1];

    for (int t = 0; t < KK; ++t) {
        int tap = t + rot; if (tap >= KK) tap -= KK;
        int ty = tap / 3 - 1;
        int tx = tap % 3 - 1;
        bf16* Sw = &S[t & 1][0];

        // ---- sampling body 0 ----
        body(n0, pimg0, oy0, ox0, ty, tx, Sw);

        // ---- A-frag prefetch (8): issued here so body-1's work + the
        //      barrier drain cover their L2 latency ----
        const bf16* ap0 = wq +
            ((size_t)(((mt * KSTEPS) + tap * 16 + kh * 8) * 64 + lane)) * 8;
        bf16x8 af[8];
        #pragma unroll
        for (int s = 0; s < 8; ++s)
            af[s] = *reinterpret_cast<const bf16x8*>(ap0 + (size_t)s * 512);

        // ---- sampling body 1 ----
        body(n1, pimg1, oy1, ox1, ty, tx, Sw);

        __syncthreads();

        // ---- off prefetch for tap t+1 (flies across the GEMM) ----
        if (t < KK - 1) {
            int tn = tap + 1; if (tn >= KK) tn = 0;
            oy0 = off[obase + (2 * tn)     * 4096 + pimg0];
            ox0 = off[obase + (2 * tn + 1) * 4096 + pimg0];
            oy1 = off[obase + (2 * tn)     * 4096 + pimg1];
            ox1 = off[obase + (2 * tn + 1) * 4096 + pimg1];
        }

        // ---- GEMM: this wave's K-half x 64 px (2 ntiles) ----
        const bf16* Sr = Sw;
        #pragma unroll
        for (int s = 0; s < 8; ++s) {
            int g  = (kh * 8 + s) * 2 + half;   // 16B granule (cin base >> 3)
            int gs = g ^ l32;                   // row & 31 == l32 for both nt
            bf16x8 b0 = *reinterpret_cast<const bf16x8*>(Sr + l32 * 256 + gs * 8);
            bf16x8 b1 = *reinterpret_cast<const bf16x8*>(Sr + (32 + l32) * 256 + gs * 8);
            acc0 = __builtin_amdgcn_mfma_f32_32x32x16_bf16(af[s], b0, acc0, 0, 0, 0);
            acc1 = __builtin_amdgcn_mfma_f32_32x32x16_bf16(af[s], b1, acc1, 0, 0, 0);
        }
        // next tap writes the OTHER buffer; re-write of this buffer (t+2)
        // is ordered behind barrier t+1.
    }

    // ---- epilogue: sum the two K-halves through LDS, then store ----
    __syncthreads();                 // all GEMM reads of S done
    float* Sf = reinterpret_cast<float*>(&S[0][0]);   // 16384 f32 = 64 KB
    if (kh == 1) {
        #pragma unroll
        for (int r = 0; r < 16; ++r) {
            Sf[((mt * 2 + 0) * 16 + r) * 64 + lane] = acc0[r];
            Sf[((mt * 2 + 1) * 16 + r) * 64 + lane] = acc1[r];
        }
    }
    __syncthreads();
    if (kh == 0) {
        // C/D layout (32x32x16): col = lane&31, row = (r&3)+8*(r>>2)+4*half
        int m = mt * 32;
        #pragma unroll
        for (int nt = 0; nt < 2; ++nt) {
            int px = pimgb + nt * 32 + l32;
            float* op = out + ((size_t)(b * 256 + m)) * 4096 + px;
            #pragma unroll
            for (int r = 0; r < 16; ++r) {
                int row = (r & 3) + 8 * (r >> 2) + half * 4;
                float a = (nt == 0) ? acc0[r] : acc1[r];
                float v = a + Sf[((mt * 2 + nt) * 16 + r) * 64 + lane]
                            + bias[m + row];
                op[(size_t)row * 4096] = v;
            }
        }
    }
}

// ---------------------------------------------------------------------------
extern "C" void kernel_launch(void* const* d_in, const int* in_sizes, int n_in,
                              void* d_out, int out_size, void* d_ws, size_t ws_size,
                              hipStream_t stream) {
    const float* x    = (const float*)d_in[0];   // [4,256,64,64]
    const float* off  = (const float*)d_in[1];   // [4,18,64,64]
    const float* w    = (const float*)d_in[2];   // [256,256,3,3]
    const float* bias = (const float*)d_in[3];   // [256]
    float* out = (float*)d_out;                  // [4,256,64,64]

    bf16* wq = (bf16*)d_ws;                               // 1,179,648 B
    bf16* xt = (bf16*)((char*)d_ws + (size_t)589824 * 2); // 8,388,608 B

    prep2_k<<<1056, 256, 0, stream>>>(x, w, xt, wq);
    deform_gemm_k<<<256, 1024, 0, stream>>>(xt, off, wq, bias, out);
}